// Round 1
// baseline (694.004 us; speedup 1.0000x reference)
//
#include <hip/hip_runtime.h>
#include <cstddef>

#define BB   16384
#define TT_  100
#define FF   64
#define HH   5
#define K4   20
#define NOUT 3

__device__ __forceinline__ float sigf(float x) {
    // 1/(1+e^-x); rcp is ~1ulp, fine vs 5.9e-4 abs threshold
    return __builtin_amdgcn_rcpf(1.0f + __expf(-x));
}
__device__ __forceinline__ float tanhf_fast(float x) {
    // tanh(x) = 1 - 2/(e^{2x}+1); safe at +/-inf (no inf/inf)
    return 1.0f - 2.0f * __builtin_amdgcn_rcpf(__expf(2.0f * x) + 1.0f);
}

// ---------------------------------------------------------------------------
// Kernel 1: xz[t][k][b] = sum_f x[b][t][f] * W1[f][k] + b1[k]
// Tile: 64 batches x 2 timesteps per block, 256 threads.
// Wave w handles k-range [5w, 5w+5) (wave-uniform -> W reads are LDS broadcast).
// ---------------------------------------------------------------------------
__global__ __launch_bounds__(256, 4) void proj_kernel(
    const float* __restrict__ x,    // [B][T][F]
    const float* __restrict__ W1,   // [F][K4]
    const float* __restrict__ b1,   // [K4]
    float* __restrict__ xz)         // [T][K4][B]
{
    __shared__ float sW[K4][FF];        // W1 transposed: sW[k][f]
    __shared__ float sX[2][64][65];     // +1 pad: bank = (b+f)%32, 2-way = free

    const int tid = threadIdx.x;
    const int t0  = blockIdx.x * 2;
    const int b0  = blockIdx.y * 64;

    // load W1 transposed into LDS
    for (int i = tid; i < FF * K4; i += 256) {
        int f = i / K4, k = i % K4;
        sW[k][f] = W1[i];
    }
    // stage x tile: 128 rows (64 b x 2 t), 16 float4-chunks per row
    for (int c = tid; c < 2048; c += 256) {
        int row = c >> 4;              // 0..127
        int bl  = row >> 1, tt = row & 1;
        int f4  = (c & 15) << 2;
        const float4 v = *(const float4*)(x + ((size_t)(b0 + bl) * TT_ + (t0 + tt)) * FF + f4);
        sX[tt][bl][f4 + 0] = v.x;
        sX[tt][bl][f4 + 1] = v.y;
        sX[tt][bl][f4 + 2] = v.z;
        sX[tt][bl][f4 + 3] = v.w;
    }
    __syncthreads();

    const int b  = tid & 63;           // lane -> batch (coalesced stores)
    const int kq = tid >> 6;           // wave index 0..3 -> k-group
    const int k0 = kq * 5;

    float acc0[5], acc1[5];
#pragma unroll
    for (int j = 0; j < 5; ++j) { float bj = b1[k0 + j]; acc0[j] = bj; acc1[j] = bj; }

#pragma unroll
    for (int fc = 0; fc < 16; ++fc) {
        float4 w[5];
#pragma unroll
        for (int j = 0; j < 5; ++j) w[j] = *(const float4*)&sW[k0 + j][fc * 4];  // uniform: broadcast
#pragma unroll
        for (int q = 0; q < 4; ++q) {
            float xv0 = sX[0][b][fc * 4 + q];
            float xv1 = sX[1][b][fc * 4 + q];
#pragma unroll
            for (int j = 0; j < 5; ++j) {
                float wv = ((const float*)&w[j])[q];
                acc0[j] = fmaf(xv0, wv, acc0[j]);
                acc1[j] = fmaf(xv1, wv, acc1[j]);
            }
        }
    }

#pragma unroll
    for (int j = 0; j < 5; ++j) {
        xz[((size_t)(t0 + 0) * K4 + k0 + j) * BB + b0 + b] = acc0[j];
        xz[((size_t)(t0 + 1) * K4 + k0 + j) * BB + b0 + b] = acc1[j];
    }
}

// ---------------------------------------------------------------------------
// Kernel 2: 3-layer LSTM recurrence + output head.
// 8 lanes per batch element: lane u (u<5 active, 5..7 duplicate u=4) owns gate
// components k = j*5+u for j=0..3 (i.e. i[u],f[u],g[u],o[u]) -> cell update is
// thread-local; h (5 floats) all-gathered via 5 shuffles per layer.
// All recurrent weights held in VGPRs. xz loads prefetched 2 steps ahead.
// ---------------------------------------------------------------------------
__global__ __launch_bounds__(256, 2) void lstm_kernel(
    const float* __restrict__ xz,   // [T][K4][B]
    const float* __restrict__ U1,
    const float* __restrict__ W2, const float* __restrict__ U2, const float* __restrict__ b2,
    const float* __restrict__ W3, const float* __restrict__ U3, const float* __restrict__ b3,
    const float* __restrict__ Wd, const float* __restrict__ bd,
    float* __restrict__ out)        // [B][NOUT]
{
    const int tid  = threadIdx.x;
    const int lane = tid & 63;
    const int u    = lane & 7;
    const int ue   = (u < 5) ? u : 4;      // dup lanes mirror unit 4
    const int base = lane & ~7;            // shuffle base within wave
    const int b    = blockIdx.x * 32 + (tid >> 3);

    // per-thread weight columns (k = j*5 + ue)
    float u1w[4][5], w2w[4][5], u2w[4][5], w3w[4][5], u3w[4][5];
    float bb2[4], bb3[4];
#pragma unroll
    for (int j = 0; j < 4; ++j) {
        const int k = j * 5 + ue;
#pragma unroll
        for (int d = 0; d < 5; ++d) {
            u1w[j][d] = U1[d * K4 + k];
            w2w[j][d] = W2[d * K4 + k];
            u2w[j][d] = U2[d * K4 + k];
            w3w[j][d] = W3[d * K4 + k];
            u3w[j][d] = U3[d * K4 + k];
        }
        bb2[j] = b2[k];
        bb3[j] = b3[k];
    }
    const int uo = (u < NOUT) ? u : 0;
    float wdw[5];
    const float bdw = bd[uo];
#pragma unroll
    for (int d = 0; d < 5; ++d) wdw[d] = Wd[d * NOUT + uo];

    float h1[5] = {0,0,0,0,0}, h2[5] = {0,0,0,0,0}, h3[5] = {0,0,0,0,0};
    float c1 = 0.f, c2 = 0.f, c3 = 0.f;

    // software pipeline, depth 2
    float cur[4], nxt[4];
#pragma unroll
    for (int j = 0; j < 4; ++j) cur[j] = xz[(size_t)(0 * K4 + j * 5 + ue) * BB + b];
#pragma unroll
    for (int j = 0; j < 4; ++j) nxt[j] = xz[(size_t)(1 * K4 + j * 5 + ue) * BB + b];

    for (int t = 0; t < TT_; ++t) {
        float pre[4];
        const int t2 = (t + 2 < TT_) ? (t + 2) : (TT_ - 1);
#pragma unroll
        for (int j = 0; j < 4; ++j) pre[j] = xz[((size_t)t2 * K4 + j * 5 + ue) * BB + b];

        float z[4];
        // ---- layer 1
#pragma unroll
        for (int j = 0; j < 4; ++j) {
            float s = cur[j];
#pragma unroll
            for (int d = 0; d < 5; ++d) s = fmaf(h1[d], u1w[j][d], s);
            z[j] = s;
        }
        {
            float iv = sigf(z[0]), fv = sigf(z[1]), gv = tanhf_fast(z[2]), ov = sigf(z[3]);
            c1 = fmaf(fv, c1, iv * gv);
            float ho = ov * tanhf_fast(c1);
#pragma unroll
            for (int d = 0; d < 5; ++d) h1[d] = __shfl(ho, base + d, 64);
        }
        // ---- layer 2
#pragma unroll
        for (int j = 0; j < 4; ++j) {
            float s = bb2[j];
#pragma unroll
            for (int d = 0; d < 5; ++d) s = fmaf(h1[d], w2w[j][d], s);
#pragma unroll
            for (int d = 0; d < 5; ++d) s = fmaf(h2[d], u2w[j][d], s);
            z[j] = s;
        }
        {
            float iv = sigf(z[0]), fv = sigf(z[1]), gv = tanhf_fast(z[2]), ov = sigf(z[3]);
            c2 = fmaf(fv, c2, iv * gv);
            float ho = ov * tanhf_fast(c2);
#pragma unroll
            for (int d = 0; d < 5; ++d) h2[d] = __shfl(ho, base + d, 64);
        }
        // ---- layer 3
#pragma unroll
        for (int j = 0; j < 4; ++j) {
            float s = bb3[j];
#pragma unroll
            for (int d = 0; d < 5; ++d) s = fmaf(h2[d], w3w[j][d], s);
#pragma unroll
            for (int d = 0; d < 5; ++d) s = fmaf(h3[d], u3w[j][d], s);
            z[j] = s;
        }
        {
            float iv = sigf(z[0]), fv = sigf(z[1]), gv = tanhf_fast(z[2]), ov = sigf(z[3]);
            c3 = fmaf(fv, c3, iv * gv);
            float ho = ov * tanhf_fast(c3);
#pragma unroll
            for (int d = 0; d < 5; ++d) h3[d] = __shfl(ho, base + d, 64);
        }

#pragma unroll
        for (int j = 0; j < 4; ++j) { cur[j] = nxt[j]; nxt[j] = pre[j]; }
    }

    // output head: out[b][u] for u<3
    if (u < NOUT) {
        float s = bdw;
#pragma unroll
        for (int d = 0; d < 5; ++d) s = fmaf(h3[d], wdw[d], s);
        out[b * NOUT + u] = s;
    }
}

extern "C" void kernel_launch(void* const* d_in, const int* in_sizes, int n_in,
                              void* d_out, int out_size, void* d_ws, size_t ws_size,
                              hipStream_t stream) {
    const float* x   = (const float*)d_in[0];
    const float* W1  = (const float*)d_in[1];
    const float* U1  = (const float*)d_in[2];
    const float* b1  = (const float*)d_in[3];
    const float* W2  = (const float*)d_in[4];
    const float* U2  = (const float*)d_in[5];
    const float* b2  = (const float*)d_in[6];
    const float* W3  = (const float*)d_in[7];
    const float* U3  = (const float*)d_in[8];
    const float* b3  = (const float*)d_in[9];
    const float* Wd  = (const float*)d_in[10];
    const float* bdp = (const float*)d_in[11];
    float* out = (float*)d_out;
    float* xz  = (float*)d_ws;   // needs T*K4*B*4 = 131072000 bytes

    dim3 g1(TT_ / 2, BB / 64);   // 50 x 256 blocks
    proj_kernel<<<g1, 256, 0, stream>>>(x, W1, b1, xz);
    lstm_kernel<<<BB / 32, 256, 0, stream>>>(xz, U1, W2, U2, b2, W3, U3, b3, Wd, bdp, out);
}